// Round 5
// baseline (548.771 us; speedup 1.0000x reference)
//
#include <hip/hip_runtime.h>
#include <hip/hip_bf16.h>
#include <cstdint>
#include <cstddef>

#define NB 8
#define NN 1024
#define ND 256
#define NH 8
#define HD 32

typedef __attribute__((ext_vector_type(8))) short bf16x8;
typedef __attribute__((ext_vector_type(4))) float f32x4;

static __device__ __forceinline__ float dot4(float4 a, float4 b) {
    return a.x * b.x + a.y * b.y + a.z * b.z + a.w * b.w;
}

static __device__ __forceinline__ uint32_t pack2bf(float x, float y) {
    __hip_bfloat16 bx = __float2bfloat16(x), by = __float2bfloat16(y);
    return (uint32_t)(*reinterpret_cast<uint16_t*>(&bx)) |
           ((uint32_t)(*reinterpret_cast<uint16_t*>(&by)) << 16);
}

// ---------------------------------------------------------------------------
// Stage A1: per-(b,c) shifted sums of the 32x32 channel image.
// mean(conv3x3_samepad(x)) is linear: S[b,c,di,dj] from total/rows/cols/corners.
// ---------------------------------------------------------------------------
__global__ __launch_bounds__(256) void conv_sums_k(const float* __restrict__ x,
                                                   float* __restrict__ S) {
    const int b = blockIdx.y;
    const int q = blockIdx.x;
    const int c = threadIdx.x;
    const float* xb = x + (size_t)b * (NN * ND) + c;
    float T = 0.f, R0 = 0.f, R31 = 0.f, C0 = 0.f, C31 = 0.f;
    float c00 = 0.f, c0N = 0.f, cN0 = 0.f, cNN = 0.f;
    const int n0 = q * 256;
    for (int nn = 0; nn < 256; ++nn) {
        const int n = n0 + nn;
        const float v = xb[(size_t)n * ND];
        T += v;
        if (n < 32)   R0 += v;
        if (n >= 992) R31 += v;
        const int j = n & 31;
        if (j == 0)  C0 += v;
        if (j == 31) C31 += v;
        if (n == 0)    c00 = v;
        if (n == 31)   c0N = v;
        if (n == 992)  cN0 = v;
        if (n == 1023) cNN = v;
    }
    float* Sp = S + (size_t)b * 2304 + c * 9;
    atomicAdd(&Sp[0], T - R31 - C31 + cNN);
    atomicAdd(&Sp[1], T - R31);
    atomicAdd(&Sp[2], T - R31 - C0 + cN0);
    atomicAdd(&Sp[3], T - C31);
    atomicAdd(&Sp[4], T);
    atomicAdd(&Sp[5], T - C0);
    atomicAdd(&Sp[6], T - R0 - C31 + c0N);
    atomicAdd(&Sp[7], T - R0);
    atomicAdd(&Sp[8], T - R0 - C0 + c00);
}

// ---------------------------------------------------------------------------
// Stage A2: pooled -> phy -> coef[b,h] = scale*scat/(atten+1e-6). One block.
// ---------------------------------------------------------------------------
__global__ __launch_bounds__(256) void pooled_phy_k(const float* __restrict__ S,
                                                    const float* __restrict__ conv_w,
                                                    const float* __restrict__ conv_b,
                                                    const float* __restrict__ phy_w,
                                                    const float* __restrict__ phy_b,
                                                    float* __restrict__ coef) {
    __shared__ float pooled_s[8][32];
    __shared__ float phy_s[8][16];
    const int tid = threadIdx.x;
    const int b = tid & 7, o = tid >> 3;
    const float4* w4 = (const float4*)(conv_w + (size_t)o * 2304);
    const float4* s4 = (const float4*)(S + (size_t)b * 2304);
    float acc = 0.f;
    for (int t = 0; t < 576; ++t) acc += dot4(w4[t], s4[t]);
    pooled_s[b][o] = conv_b[o] + acc * (1.f / 1024.f);
    __syncthreads();
    if (tid < 128) {
        const int b2 = tid & 7, oo = tid >> 3;
        float a = phy_b[oo];
#pragma unroll
        for (int l = 0; l < 32; ++l) a += pooled_s[b2][l] * phy_w[oo * 32 + l];
        phy_s[b2][oo] = a;
    }
    __syncthreads();
    if (tid < 64) {
        const int b3 = tid & 7, hh = tid >> 3;
        coef[b3 * 8 + hh] = 0.17677669529663687f * phy_s[b3][8 + hh] /
                            (phy_s[b3][hh] + 1e-6f);
    }
}

// ---------------------------------------------------------------------------
// Stage B: physics flash attention (f32). Per (b,h): S = coef*(Q Q^T),
// online softmax, O = A Q. Unchanged desk-checked structure.
// ---------------------------------------------------------------------------
__global__ __launch_bounds__(256) void phys_attn_k(const float* __restrict__ x,
                                                   const float* __restrict__ coef,
                                                   float* __restrict__ attn_out) {
    const int bh = blockIdx.y;
    const int b = bh >> 3, h = bh & 7;
    const int r0 = blockIdx.x * 64;
    const float cf = coef[bh];
    __shared__ __align__(16) float qs[64][32];
    __shared__ __align__(16) float ks[64][32];
    __shared__ __align__(16) float ps[64][68];
    const int tid = threadIdx.x;
    const int tx = tid & 15, ty = tid >> 4;
    const float* xb = x + (size_t)b * (NN * ND) + h * HD;

    {
        const int r = tid >> 2, c4 = (tid & 3) * 8;
        const float* src = xb + (size_t)(r0 + r) * ND + c4;
        const int sw = (r >> 2) & 7;
        const int s0 = ((c4 >> 2) ^ sw) << 2;
        const int s1 = (((c4 >> 2) + 1) ^ sw) << 2;
        *(float4*)&qs[r][s0] = *(const float4*)&src[0];
        *(float4*)&qs[r][s1] = *(const float4*)&src[4];
    }

    float acc0[4], acc1[4], m[4], l[4];
#pragma unroll
    for (int ri = 0; ri < 4; ++ri) { acc0[ri] = 0.f; acc1[ri] = 0.f; m[ri] = -3.0e38f; l[ri] = 0.f; }

    for (int ct = 0; ct < 16; ++ct) {
        __syncthreads();
        {
            const int r = tid >> 2, c4 = (tid & 3) * 8;
            const float* src = xb + (size_t)(ct * 64 + r) * ND + c4;
            const int sw = (r >> 2) & 7;
            const int s0 = ((c4 >> 2) ^ sw) << 2;
            const int s1 = (((c4 >> 2) + 1) ^ sw) << 2;
            *(float4*)&ks[r][s0] = *(const float4*)&src[0];
            *(float4*)&ks[r][s1] = *(const float4*)&src[4];
        }
        __syncthreads();

        float s[4][4];
#pragma unroll
        for (int ri = 0; ri < 4; ++ri)
#pragma unroll
            for (int ci = 0; ci < 4; ++ci) s[ri][ci] = 0.f;

#pragma unroll
        for (int t4 = 0; t4 < 8; ++t4) {
            float4 a[4], kb[4];
#pragma unroll
            for (int ri = 0; ri < 4; ++ri)
                a[ri] = *(const float4*)&qs[ty * 4 + ri][(t4 ^ (ty & 7)) << 2];
#pragma unroll
            for (int ci = 0; ci < 4; ++ci)
                kb[ci] = *(const float4*)&ks[tx * 4 + ci][(t4 ^ (tx & 7)) << 2];
#pragma unroll
            for (int ri = 0; ri < 4; ++ri)
#pragma unroll
                for (int ci = 0; ci < 4; ++ci)
                    s[ri][ci] += dot4(a[ri], kb[ci]);
        }

#pragma unroll
        for (int ri = 0; ri < 4; ++ri) {
            float p[4];
            float mt = -3.0e38f;
#pragma unroll
            for (int ci = 0; ci < 4; ++ci) { s[ri][ci] *= cf; mt = fmaxf(mt, s[ri][ci]); }
            mt = fmaxf(mt, __shfl_xor(mt, 1));
            mt = fmaxf(mt, __shfl_xor(mt, 2));
            mt = fmaxf(mt, __shfl_xor(mt, 4));
            mt = fmaxf(mt, __shfl_xor(mt, 8));
            const float mn = fmaxf(m[ri], mt);
            const float corr = __expf(m[ri] - mn);
            float rs = 0.f;
#pragma unroll
            for (int ci = 0; ci < 4; ++ci) { p[ci] = __expf(s[ri][ci] - mn); rs += p[ci]; }
            rs += __shfl_xor(rs, 1);
            rs += __shfl_xor(rs, 2);
            rs += __shfl_xor(rs, 4);
            rs += __shfl_xor(rs, 8);
            l[ri] = l[ri] * corr + rs;
            m[ri] = mn;
            acc0[ri] *= corr; acc1[ri] *= corr;
            *(float4*)&ps[ty * 4 + ri][tx * 4] = make_float4(p[0], p[1], p[2], p[3]);
        }
        __syncthreads();

#pragma unroll 4
        for (int c = 0; c < 64; ++c) {
            const int col = ((((tx >> 1) ^ ((c >> 2) & 7)) << 2) | ((tx * 2) & 3));
            const float2 kv = *(const float2*)&ks[c][col];
#pragma unroll
            for (int ri = 0; ri < 4; ++ri) {
                const float pv = ps[ty * 4 + ri][c];
                acc0[ri] += pv * kv.x;
                acc1[ri] += pv * kv.y;
            }
        }
    }
#pragma unroll
    for (int ri = 0; ri < 4; ++ri) {
        const float inv = 1.f / l[ri];
        const size_t o = (size_t)(b * NN + r0 + ty * 4 + ri) * ND + h * HD + tx * 2;
        float2 ov; ov.x = acc0[ri] * inv; ov.y = acc1[ri] * inv;
        *(float2*)&attn_out[o] = ov;
    }
}

// ---------------------------------------------------------------------------
// Generic f32 GEMM (kept for the tiny envk GEMM and as MFMA fallback).
// ---------------------------------------------------------------------------
__global__ __launch_bounds__(256) void gemm_tn_k(const float* __restrict__ A,
                                                 const float* __restrict__ W,
                                                 const float* __restrict__ bias,
                                                 float* __restrict__ C,
                                                 int M, int N, int K) {
    __shared__ __align__(16) float As[32][64];
    __shared__ __align__(16) float Ws[32][64];
    const int tid = threadIdx.x;
    const int m0 = blockIdx.x * 64, n0 = blockIdx.y * 64;
    const int tx = tid & 15, ty = tid >> 4;
    const int lrow = tid >> 2, lc4 = (tid & 3) * 4;
    float acc[4][4] = {{0.f}};
    for (int k0 = 0; k0 < K; k0 += 32) {
        {
            const float* a = A + (size_t)(m0 + lrow) * K + k0 + lc4;
            const float4 v0 = *(const float4*)&a[0];
            const float4 v1 = *(const float4*)&a[16];
            As[lc4 + 0][lrow] = v0.x; As[lc4 + 1][lrow] = v0.y;
            As[lc4 + 2][lrow] = v0.z; As[lc4 + 3][lrow] = v0.w;
            As[lc4 + 16][lrow] = v1.x; As[lc4 + 17][lrow] = v1.y;
            As[lc4 + 18][lrow] = v1.z; As[lc4 + 19][lrow] = v1.w;
            const float* w = W + (size_t)(n0 + lrow) * K + k0 + lc4;
            const float4 u0 = *(const float4*)&w[0];
            const float4 u1 = *(const float4*)&w[16];
            Ws[lc4 + 0][lrow] = u0.x; Ws[lc4 + 1][lrow] = u0.y;
            Ws[lc4 + 2][lrow] = u0.z; Ws[lc4 + 3][lrow] = u0.w;
            Ws[lc4 + 16][lrow] = u1.x; Ws[lc4 + 17][lrow] = u1.y;
            Ws[lc4 + 18][lrow] = u1.z; Ws[lc4 + 19][lrow] = u1.w;
        }
        __syncthreads();
#pragma unroll
        for (int kk = 0; kk < 32; ++kk) {
            const float4 av = *(const float4*)&As[kk][ty * 4];
            const float4 wv = *(const float4*)&Ws[kk][tx * 4];
            const float a_[4] = {av.x, av.y, av.z, av.w};
            const float w_[4] = {wv.x, wv.y, wv.z, wv.w};
#pragma unroll
            for (int ri = 0; ri < 4; ++ri)
#pragma unroll
                for (int ci = 0; ci < 4; ++ci)
                    acc[ri][ci] = fmaf(a_[ri], w_[ci], acc[ri][ci]);
        }
        __syncthreads();
    }
#pragma unroll
    for (int ri = 0; ri < 4; ++ri)
#pragma unroll
        for (int ci = 0; ci < 4; ++ci) {
            const int row = m0 + ty * 4 + ri, col = n0 + tx * 4 + ci;
            C[(size_t)row * N + col] = acc[ri][ci] + bias[col];
        }
}

// ---------------------------------------------------------------------------
// bf16 MFMA GEMM: C[M,256] = A[M,K]@W[256,K]^T + bias, f32 in/out, bf16
// compute via mfma_f32_16x16x32_bf16. Tile 64x64, BK=64, 4 waves, each wave
// a 32x32 sub-tile (2x2 fragments). GATE=1: K=512 split over [Aout|Aoute],
// epilogue sigmoid-blend into out.
// Layout facts (HW-verified, m89/m91): A-frag lane holds row=l&15,
// k=(l>>4)*8+i ; B-frag lane holds col=l&15, same k-chunk; D col=l&15,
// row=(l>>4)*4+reg. LDS rows padded to 72 bf16 (144 B = 9 slots).
// ---------------------------------------------------------------------------
template <int GATE>
__global__ __launch_bounds__(256) void mfma_gemm_k(const float* __restrict__ A,
                                                   const float* __restrict__ A2,
                                                   const float* __restrict__ W,
                                                   const float* __restrict__ bias,
                                                   float* __restrict__ C,
                                                   int M, int K) {
    __shared__ ushort As[64][72];
    __shared__ ushort Ws[64][72];
    const int tid = threadIdx.x;
    const int m0 = blockIdx.x * 64, n0 = blockIdx.y * 64;
    const int w = tid >> 6, lane = tid & 63;
    const int wr = w >> 1, wc = w & 1;
    const int lr = lane & 15, lk = (lane >> 4) * 8;
    const int srow = tid >> 2, sc16 = (tid & 3) * 16;
    const int lda = GATE ? 256 : K;

    f32x4 acc[2][2];
#pragma unroll
    for (int i = 0; i < 2; ++i)
#pragma unroll
        for (int j = 0; j < 2; ++j) acc[i][j] = (f32x4){0.f, 0.f, 0.f, 0.f};

    const int nk = K / 64;
    for (int kt = 0; kt < nk; ++kt) {
        const float* srcA;
        int ka;
        if (GATE) {
            if (kt < 4) { srcA = A;  ka = kt * 64; }
            else        { srcA = A2; ka = (kt - 4) * 64; }
        } else { srcA = A; ka = kt * 64; }

        {   // stage A-tile and W-tile (f32 -> bf16)
            const float* pa = srcA + (size_t)(m0 + srow) * lda + ka + sc16;
            const float* pw = W + (size_t)(n0 + srow) * K + kt * 64 + sc16;
#pragma unroll
            for (int q = 0; q < 4; ++q) {
                const float4 va = *(const float4*)&pa[q * 4];
                uint2 ua; ua.x = pack2bf(va.x, va.y); ua.y = pack2bf(va.z, va.w);
                *(uint2*)&As[srow][sc16 + q * 4] = ua;
                const float4 vw = *(const float4*)&pw[q * 4];
                uint2 uw; uw.x = pack2bf(vw.x, vw.y); uw.y = pack2bf(vw.z, vw.w);
                *(uint2*)&Ws[srow][sc16 + q * 4] = uw;
            }
        }
        __syncthreads();
#pragma unroll
        for (int kk = 0; kk < 2; ++kk) {
            bf16x8 af[2], bf[2];
#pragma unroll
            for (int fm = 0; fm < 2; ++fm)
                af[fm] = *(const bf16x8*)&As[wr * 32 + fm * 16 + lr][kk * 32 + lk];
#pragma unroll
            for (int fn = 0; fn < 2; ++fn)
                bf[fn] = *(const bf16x8*)&Ws[wc * 32 + fn * 16 + lr][kk * 32 + lk];
#pragma unroll
            for (int fm = 0; fm < 2; ++fm)
#pragma unroll
                for (int fn = 0; fn < 2; ++fn)
                    acc[fm][fn] = __builtin_amdgcn_mfma_f32_16x16x32_bf16(
                        af[fm], bf[fn], acc[fm][fn], 0, 0, 0);
        }
        __syncthreads();
    }

#pragma unroll
    for (int fm = 0; fm < 2; ++fm)
#pragma unroll
        for (int fn = 0; fn < 2; ++fn) {
#pragma unroll
            for (int j = 0; j < 4; ++j) {
                const int row = m0 + wr * 32 + fm * 16 + (lane >> 4) * 4 + j;
                const int col = n0 + wc * 32 + fn * 16 + lr;
                const float v = acc[fm][fn][j] + bias[col];
                if (GATE) {
                    const float g = 1.f / (1.f + __expf(-v));
                    const float o  = A[(size_t)row * 256 + col];
                    const float oe = A2[(size_t)row * 256 + col];
                    C[(size_t)row * 256 + col] = g * o + (1.f - g) * oe;
                } else {
                    C[(size_t)row * 256 + col] = v;
                }
            }
        }
}

// ---------------------------------------------------------------------------
// Stage C: per-z env attention (f32, unchanged; reference z-quirks kept).
// ---------------------------------------------------------------------------
__global__ __launch_bounds__(256) void env_attn_k(const float* __restrict__ Qp,
                                                  const float* __restrict__ Kp,
                                                  const float* __restrict__ Vp,
                                                  const float* __restrict__ envk,
                                                  const float* __restrict__ lam_p,
                                                  float* __restrict__ oute_pre) {
    const int gtid = blockIdx.x * 256 + threadIdx.x;
    const int z = gtid & 8191, b = gtid >> 13;
    const int i = z >> 3, j = z & 7, j2 = z >> 10;
    const float lam = lam_p[0];
    const float rs32 = 0.17677669529663687f;

    float4 q[8];
    const float* qrow = Qp + ((size_t)b * NN + i) * ND + j * HD;
#pragma unroll
    for (int t = 0; t < 8; ++t) q[t] = *(const float4*)&qrow[t * 4];

    float s[72];
    float mx = -3.0e38f;
#pragma unroll
    for (int c = 0; c < 8; ++c) {
        const float* kr = Kp + ((size_t)c * NN + i) * ND + j * HD;
        float d = 0.f;
#pragma unroll
        for (int t = 0; t < 8; ++t) d += dot4(q[t], *(const float4*)&kr[t * 4]);
        s[c] = d * rs32;
        mx = fmaxf(mx, s[c]);
    }
#pragma unroll
    for (int e = 0; e < 64; ++e) {
        const float* er = envk + (size_t)e * ND + j * HD;
        float d = 0.f;
#pragma unroll
        for (int t = 0; t < 8; ++t) d += dot4(q[t], *(const float4*)&er[t * 4]);
        s[8 + e] = lam * d * rs32;
        mx = fmaxf(mx, s[8 + e]);
    }
    float sum = 0.f;
#pragma unroll
    for (int k = 0; k < 72; ++k) { s[k] = __expf(s[k] - mx); sum += s[k]; }
    const float inv = 1.f / sum;

    float4 o[8];
#pragma unroll
    for (int t = 0; t < 8; ++t) o[t] = make_float4(0.f, 0.f, 0.f, 0.f);
#pragma unroll
    for (int c = 0; c < 8; ++c) {
        const float* vr = Vp + ((size_t)c * NN + i) * ND + j * HD;
        const float w = s[c] * inv;
#pragma unroll
        for (int t = 0; t < 8; ++t) {
            const float4 v = *(const float4*)&vr[t * 4];
            o[t].x += w * v.x; o[t].y += w * v.y; o[t].z += w * v.z; o[t].w += w * v.w;
        }
    }
#pragma unroll
    for (int e = 0; e < 64; ++e) {
        const float* er = envk + (size_t)e * ND + j2 * HD;
        const float w = s[8 + e] * inv;
#pragma unroll
        for (int t = 0; t < 8; ++t) {
            const float4 v = *(const float4*)&er[t * 4];
            o[t].x += w * v.x; o[t].y += w * v.y; o[t].z += w * v.z; o[t].w += w * v.w;
        }
    }
    float* orow = oute_pre + ((size_t)b * NN + i) * ND + j * HD;
#pragma unroll
    for (int t = 0; t < 8; ++t) *(float4*)&orow[t * 4] = o[t];
}

extern "C" void kernel_launch(void* const* d_in, const int* in_sizes, int n_in,
                              void* d_out, int out_size, void* d_ws, size_t ws_size,
                              hipStream_t stream) {
    const float* x          = (const float*)d_in[0];
    const float* conv_w     = (const float*)d_in[1];
    const float* conv_b     = (const float*)d_in[2];
    const float* phy_w      = (const float*)d_in[3];
    const float* phy_b      = (const float*)d_in[4];
    const float* to_out_w   = (const float*)d_in[5];
    const float* to_out_b   = (const float*)d_in[6];
    const float* env_keys   = (const float*)d_in[7];
    const float* env_proj_w = (const float*)d_in[8];
    const float* env_proj_b = (const float*)d_in[9];
    const float* lambda_    = (const float*)d_in[10];
    const float* q_w        = (const float*)d_in[11];
    const float* q_b        = (const float*)d_in[12];
    const float* k_w        = (const float*)d_in[13];
    const float* k_b        = (const float*)d_in[14];
    const float* v_w        = (const float*)d_in[15];
    const float* v_b        = (const float*)d_in[16];
    const float* out_proj_w = (const float*)d_in[17];
    const float* out_proj_b = (const float*)d_in[18];
    const float* gate_w     = (const float*)d_in[19];
    const float* gate_b     = (const float*)d_in[20];
    (void)in_sizes; (void)n_in; (void)out_size; (void)ws_size;

    float* ws    = (float*)d_ws;
    float* Sb    = ws;                  // 18432
    float* coefw = Sb + 18432;          // 64
    float* envk  = coefw + 64;          // 16384
    float* bufA  = envk + 16384;        // 2M : attn_out -> oute_pre
    float* bufB  = bufA + 2097152;      // 2M : out (physics branch)
    float* bufC  = bufB + 2097152;      // 2M : Qp -> oute
    float* bufD  = bufC + 2097152;      // 2M : Kp
    float* Vp    = (float*)d_out;       // Vp liveness ends before gate writes

    hipMemsetAsync(Sb, 0, 18432 * sizeof(float), stream);
    conv_sums_k<<<dim3(4, 8), 256, 0, stream>>>(x, Sb);
    pooled_phy_k<<<1, 256, 0, stream>>>(Sb, conv_w, conv_b, phy_w, phy_b, coefw);

    phys_attn_k<<<dim3(16, 64), 256, 0, stream>>>(x, coefw, bufA);
    mfma_gemm_k<0><<<dim3(128, 4), 256, 0, stream>>>(bufA, nullptr, to_out_w,
                                                     to_out_b, bufB, 8192, 256);

    mfma_gemm_k<0><<<dim3(128, 4), 256, 0, stream>>>(x, nullptr, q_w, q_b, bufC,
                                                     8192, 256);
    mfma_gemm_k<0><<<dim3(128, 4), 256, 0, stream>>>(x, nullptr, k_w, k_b, bufD,
                                                     8192, 256);
    mfma_gemm_k<0><<<dim3(128, 4), 256, 0, stream>>>(x, nullptr, v_w, v_b, Vp,
                                                     8192, 256);
    gemm_tn_k<<<dim3(1, 4), 256, 0, stream>>>(env_keys, env_proj_w, env_proj_b,
                                              envk, 64, 256, 256);

    env_attn_k<<<256, 256, 0, stream>>>(bufC, bufD, Vp, envk, lambda_, bufA);
    mfma_gemm_k<0><<<dim3(128, 4), 256, 0, stream>>>(bufA, nullptr, out_proj_w,
                                                     out_proj_b, bufC, 8192, 256);

    mfma_gemm_k<1><<<dim3(128, 4), 256, 0, stream>>>(bufB, bufC, gate_w, gate_b,
                                                     (float*)d_out, 8192, 512);
}

// Round 6
// 347.017 us; speedup vs baseline: 1.5814x; 1.5814x over previous
//
#include <hip/hip_runtime.h>
#include <hip/hip_bf16.h>
#include <cstdint>
#include <cstddef>

#define NB 8
#define NN 1024
#define ND 256
#define NH 8
#define HD 32

typedef __attribute__((ext_vector_type(8))) short bf16x8;
typedef __attribute__((ext_vector_type(4))) float f32x4;

static __device__ __forceinline__ float dot4(float4 a, float4 b) {
    return a.x * b.x + a.y * b.y + a.z * b.z + a.w * b.w;
}

static __device__ __forceinline__ uint32_t pack2bf(float x, float y) {
    __hip_bfloat16 bx = __float2bfloat16(x), by = __float2bfloat16(y);
    return (uint32_t)(*reinterpret_cast<uint16_t*>(&bx)) |
           ((uint32_t)(*reinterpret_cast<uint16_t*>(&by)) << 16);
}

static __device__ __forceinline__ ushort bf1(float x) {
    __hip_bfloat16 b = __float2bfloat16(x);
    return *reinterpret_cast<ushort*>(&b);
}

// ---------------------------------------------------------------------------
// Stage A1: shifted sums for conv-mean algebra. Grid (16,8) for TLP.
// ---------------------------------------------------------------------------
__global__ __launch_bounds__(256) void conv_sums_k(const float* __restrict__ x,
                                                   float* __restrict__ S) {
    const int b = blockIdx.y;
    const int q = blockIdx.x;
    const int c = threadIdx.x;
    const float* xb = x + (size_t)b * (NN * ND) + c;
    float T = 0.f, R0 = 0.f, R31 = 0.f, C0 = 0.f, C31 = 0.f;
    float c00 = 0.f, c0N = 0.f, cN0 = 0.f, cNN = 0.f;
    const int n0 = q * 64;
    for (int nn = 0; nn < 64; ++nn) {
        const int n = n0 + nn;
        const float v = xb[(size_t)n * ND];
        T += v;
        if (n < 32)   R0 += v;
        if (n >= 992) R31 += v;
        const int j = n & 31;
        if (j == 0)  C0 += v;
        if (j == 31) C31 += v;
        if (n == 0)    c00 = v;
        if (n == 31)   c0N = v;
        if (n == 992)  cN0 = v;
        if (n == 1023) cNN = v;
    }
    float* Sp = S + (size_t)b * 2304 + c * 9;
    atomicAdd(&Sp[0], T - R31 - C31 + cNN);
    atomicAdd(&Sp[1], T - R31);
    atomicAdd(&Sp[2], T - R31 - C0 + cN0);
    atomicAdd(&Sp[3], T - C31);
    atomicAdd(&Sp[4], T);
    atomicAdd(&Sp[5], T - C0);
    atomicAdd(&Sp[6], T - R0 - C31 + c0N);
    atomicAdd(&Sp[7], T - R0);
    atomicAdd(&Sp[8], T - R0 - C0 + c00);
}

// ---------------------------------------------------------------------------
// Stage A2a: pooled[b,o] = conv_b[o] + dot(conv_w[o], S[b])/1024.
// 256 blocks (b,o) x 1 wave, shfl-reduce.
// ---------------------------------------------------------------------------
__global__ __launch_bounds__(64) void pooled_k(const float* __restrict__ S,
                                               const float* __restrict__ conv_w,
                                               const float* __restrict__ conv_b,
                                               float* __restrict__ pooled) {
    const int bx = blockIdx.x;
    const int b = bx >> 5, o = bx & 31;
    const int t = threadIdx.x;
    const float4* w4 = (const float4*)(conv_w + (size_t)o * 2304);
    const float4* s4 = (const float4*)(S + (size_t)b * 2304);
    float acc = 0.f;
#pragma unroll
    for (int f = 0; f < 9; ++f) acc += dot4(w4[f * 64 + t], s4[f * 64 + t]);
    acc += __shfl_xor(acc, 1);  acc += __shfl_xor(acc, 2);
    acc += __shfl_xor(acc, 4);  acc += __shfl_xor(acc, 8);
    acc += __shfl_xor(acc, 16); acc += __shfl_xor(acc, 32);
    if (t == 0) pooled[b * 32 + o] = conv_b[o] + acc * (1.f / 1024.f);
}

// ---------------------------------------------------------------------------
// Stage A2b: phy = pooled @ phy_w.T + phy_b ; coef = scale*scat/(atten+1e-6).
// ---------------------------------------------------------------------------
__global__ __launch_bounds__(64) void phy_coef_k(const float* __restrict__ pooled,
                                                 const float* __restrict__ phy_w,
                                                 const float* __restrict__ phy_b,
                                                 float* __restrict__ coef) {
    __shared__ float ps[8][32];
    const int t = threadIdx.x;
#pragma unroll
    for (int r = 0; r < 4; ++r) {
        const int idx = r * 64 + t;
        ps[idx >> 5][idx & 31] = pooled[idx];
    }
    __syncthreads();
    const int b = t & 7, hh = t >> 3;
    float atten = phy_b[hh], scat = phy_b[8 + hh];
#pragma unroll
    for (int l = 0; l < 32; ++l) {
        atten += ps[b][l] * phy_w[hh * 32 + l];
        scat  += ps[b][l] * phy_w[(8 + hh) * 32 + l];
    }
    coef[b * 8 + hh] = 0.17677669529663687f * scat / (atten + 1e-6f);
}

// ---------------------------------------------------------------------------
// Stage B: MFMA physics flash attention. Grid (8, 64) x 256 thr (4 waves).
// Per wave: 32 q-rows. Per 32-kv chunk:
//   S^T = mfma(A=K-rows, B=(cf*Q)-rows)  -> lane owns q at lane&15, kv rows
//   (g*4+j | fkv*16); chunk row-max/sum via shfl_xor(16/32); P=exp(S-m) packed
//   to bf16 in-register and shuffled to the A-frag layout; O += mfma(P, V^T).
// K [kv][d] and V^T [d][kv] staged in LDS (rows padded to 40 bf16 -> ~2-way
// conflicts = free per m136), double-buffered, one barrier per chunk.
// Layouts are the m89/m91 mappings HW-validated by round-5's mfma_gemm_k pass.
// ---------------------------------------------------------------------------
__global__ __launch_bounds__(256) void phys_attn_mfma_k(const float* __restrict__ x,
                                                        const float* __restrict__ coef,
                                                        float* __restrict__ attn_out) {
    const int bh = blockIdx.y;
    const int b = bh >> 3, h = bh & 7;
    const int wv = threadIdx.x >> 6, lane = threadIdx.x & 63;
    const int g = lane >> 4, c16 = lane & 15;
    const float cf = coef[bh];
    const float* xb = x + (size_t)b * (NN * ND) + h * HD;

    __shared__ ushort Kl[2][32][40];
    __shared__ ushort VT[2][32][40];

    // Q fragments (B-operand; cf folded in). Lane: row=q0+fq*16+c16, k=g*8+i.
    bf16x8 qf[2];
    const int q0 = blockIdx.x * 128 + wv * 32;
#pragma unroll
    for (int fq = 0; fq < 2; ++fq) {
        const float* qr = xb + (size_t)(q0 + fq * 16 + c16) * ND + g * 8;
        const float4 v0 = *(const float4*)&qr[0];
        const float4 v1 = *(const float4*)&qr[4];
        union { bf16x8 v; uint32_t u[4]; } qq;
        qq.u[0] = pack2bf(v0.x * cf, v0.y * cf);
        qq.u[1] = pack2bf(v0.z * cf, v0.w * cf);
        qq.u[2] = pack2bf(v1.x * cf, v1.y * cf);
        qq.u[3] = pack2bf(v1.z * cf, v1.w * cf);
        qf[fq] = qq.v;
    }

    // stage chunk 0
    const int skv = threadIdx.x >> 3, sdq = (threadIdx.x & 7) * 4;
    {
        const float4 v = *(const float4*)&xb[(size_t)skv * ND + sdq];
        const ushort e0 = bf1(v.x), e1 = bf1(v.y), e2 = bf1(v.z), e3 = bf1(v.w);
        uint2 kw; kw.x = (uint32_t)e0 | ((uint32_t)e1 << 16);
        kw.y = (uint32_t)e2 | ((uint32_t)e3 << 16);
        *(uint2*)&Kl[0][skv][sdq] = kw;
        VT[0][sdq + 0][skv] = e0; VT[0][sdq + 1][skv] = e1;
        VT[0][sdq + 2][skv] = e2; VT[0][sdq + 3][skv] = e3;
    }
    __syncthreads();

    f32x4 oacc[2][2];
#pragma unroll
    for (int i = 0; i < 2; ++i)
#pragma unroll
        for (int j = 0; j < 2; ++j) oacc[i][j] = (f32x4){0.f, 0.f, 0.f, 0.f};
    float m[2] = {-3.0e38f, -3.0e38f};
    float lsum[2] = {0.f, 0.f};

    const int srcA = c16 + (((2 * g) & 3) << 4);
    const int srcB = c16 + (((2 * g + 1) & 3) << 4);
    const int srcQ = (lane & 48) | (g * 4);  // +j at use site

    for (int c = 0; c < 16 * 2; ++c) {
        const int cur = c & 1;
        // prefetch next chunk to regs (hides HBM under compute)
        float4 nv;
        const bool hasNext = (c + 1 < 32);
        if (hasNext)
            nv = *(const float4*)&xb[(size_t)((c + 1) * 32 + skv) * ND + sdq];

        // QK^T (swapped): S^T tiles
        const bf16x8 af0 = *(const bf16x8*)&Kl[cur][c16][g * 8];
        const bf16x8 af1 = *(const bf16x8*)&Kl[cur][16 + c16][g * 8];
        f32x4 sacc[2][2];
        const f32x4 z4 = (f32x4){0.f, 0.f, 0.f, 0.f};
        sacc[0][0] = __builtin_amdgcn_mfma_f32_16x16x32_bf16(af0, qf[0], z4, 0, 0, 0);
        sacc[0][1] = __builtin_amdgcn_mfma_f32_16x16x32_bf16(af0, qf[1], z4, 0, 0, 0);
        sacc[1][0] = __builtin_amdgcn_mfma_f32_16x16x32_bf16(af1, qf[0], z4, 0, 0, 0);
        sacc[1][1] = __builtin_amdgcn_mfma_f32_16x16x32_bf16(af1, qf[1], z4, 0, 0, 0);

        bf16x8 pa[2];
        float corrS[2];
#pragma unroll
        for (int fq = 0; fq < 2; ++fq) {
            float vmax = sacc[0][fq][0];
#pragma unroll
            for (int j = 1; j < 4; ++j) vmax = fmaxf(vmax, sacc[0][fq][j]);
#pragma unroll
            for (int j = 0; j < 4; ++j) vmax = fmaxf(vmax, sacc[1][fq][j]);
            vmax = fmaxf(vmax, __shfl_xor(vmax, 16));
            vmax = fmaxf(vmax, __shfl_xor(vmax, 32));
            const float mn = fmaxf(m[fq], vmax);
            corrS[fq] = __expf(m[fq] - mn);
            m[fq] = mn;
            float p[2][4];
            float rs = 0.f;
#pragma unroll
            for (int fkv = 0; fkv < 2; ++fkv)
#pragma unroll
                for (int j = 0; j < 4; ++j) {
                    p[fkv][j] = __expf(sacc[fkv][fq][j] - mn);
                    rs += p[fkv][j];
                }
            rs += __shfl_xor(rs, 16);
            rs += __shfl_xor(rs, 32);
            lsum[fq] = lsum[fq] * corrS[fq] + rs;

            // pack P -> bf16 pairs: pk[fkv][jp]
            uint32_t pk00 = pack2bf(p[0][0], p[0][1]);
            uint32_t pk01 = pack2bf(p[0][2], p[0][3]);
            uint32_t pk10 = pack2bf(p[1][0], p[1][1]);
            uint32_t pk11 = pack2bf(p[1][2], p[1][3]);
            // shuffle into A-frag layout: lane needs P[q=c16][kv=g*8..g*8+7]
            const int t00 = __shfl((int)pk00, srcA), t10 = __shfl((int)pk10, srcA);
            const int t01 = __shfl((int)pk01, srcA), t11 = __shfl((int)pk11, srcA);
            const int t02 = __shfl((int)pk00, srcB), t12 = __shfl((int)pk10, srcB);
            const int t03 = __shfl((int)pk01, srcB), t13 = __shfl((int)pk11, srcB);
            union { bf16x8 v; uint32_t u[4]; } pu;
            const bool hi = (g >> 1) != 0;
            pu.u[0] = (uint32_t)(hi ? t10 : t00);
            pu.u[1] = (uint32_t)(hi ? t11 : t01);
            pu.u[2] = (uint32_t)(hi ? t12 : t02);
            pu.u[3] = (uint32_t)(hi ? t13 : t03);
            pa[fq] = pu.v;
        }

        // O-rescale: corr at O-row layout (row = g*4+j)
#pragma unroll
        for (int fq = 0; fq < 2; ++fq) {
#pragma unroll
            for (int j = 0; j < 4; ++j) {
                const float cj = __shfl(corrS[fq], srcQ + j);
                oacc[fq][0][j] *= cj;
                oacc[fq][1][j] *= cj;
            }
        }

        // PV: O += P @ V  (V^T fragments as B)
        const bf16x8 bv0 = *(const bf16x8*)&VT[cur][c16][g * 8];
        const bf16x8 bv1 = *(const bf16x8*)&VT[cur][16 + c16][g * 8];
        oacc[0][0] = __builtin_amdgcn_mfma_f32_16x16x32_bf16(pa[0], bv0, oacc[0][0], 0, 0, 0);
        oacc[0][1] = __builtin_amdgcn_mfma_f32_16x16x32_bf16(pa[0], bv1, oacc[0][1], 0, 0, 0);
        oacc[1][0] = __builtin_amdgcn_mfma_f32_16x16x32_bf16(pa[1], bv0, oacc[1][0], 0, 0, 0);
        oacc[1][1] = __builtin_amdgcn_mfma_f32_16x16x32_bf16(pa[1], bv1, oacc[1][1], 0, 0, 0);

        // write staged next chunk (other buffer; safe pre-barrier)
        if (hasNext) {
            const ushort e0 = bf1(nv.x), e1 = bf1(nv.y), e2 = bf1(nv.z), e3 = bf1(nv.w);
            uint2 kw; kw.x = (uint32_t)e0 | ((uint32_t)e1 << 16);
            kw.y = (uint32_t)e2 | ((uint32_t)e3 << 16);
            *(uint2*)&Kl[cur ^ 1][skv][sdq] = kw;
            VT[cur ^ 1][sdq + 0][skv] = e0; VT[cur ^ 1][sdq + 1][skv] = e1;
            VT[cur ^ 1][sdq + 2][skv] = e2; VT[cur ^ 1][sdq + 3][skv] = e3;
        }
        __syncthreads();
    }

    // epilogue: normalize, store f32
#pragma unroll
    for (int fq = 0; fq < 2; ++fq) {
        const float inv = 1.f / lsum[fq];
#pragma unroll
        for (int j = 0; j < 4; ++j) {
            const float iv = __shfl(inv, srcQ + j);
            const int row = q0 + fq * 16 + g * 4 + j;
            float* orow = attn_out + (size_t)(b * NN + row) * ND + h * HD;
            orow[c16]      = oacc[fq][0][j] * iv;
            orow[16 + c16] = oacc[fq][1][j] * iv;
        }
    }
}

// ---------------------------------------------------------------------------
// Generic f32 GEMM (tiny envk GEMM only).
// ---------------------------------------------------------------------------
__global__ __launch_bounds__(256) void gemm_tn_k(const float* __restrict__ A,
                                                 const float* __restrict__ W,
                                                 const float* __restrict__ bias,
                                                 float* __restrict__ C,
                                                 int M, int N, int K) {
    __shared__ __align__(16) float As[32][64];
    __shared__ __align__(16) float Ws[32][64];
    const int tid = threadIdx.x;
    const int m0 = blockIdx.x * 64, n0 = blockIdx.y * 64;
    const int tx = tid & 15, ty = tid >> 4;
    const int lrow = tid >> 2, lc4 = (tid & 3) * 4;
    float acc[4][4] = {{0.f}};
    for (int k0 = 0; k0 < K; k0 += 32) {
        {
            const float* a = A + (size_t)(m0 + lrow) * K + k0 + lc4;
            const float4 v0 = *(const float4*)&a[0];
            const float4 v1 = *(const float4*)&a[16];
            As[lc4 + 0][lrow] = v0.x; As[lc4 + 1][lrow] = v0.y;
            As[lc4 + 2][lrow] = v0.z; As[lc4 + 3][lrow] = v0.w;
            As[lc4 + 16][lrow] = v1.x; As[lc4 + 17][lrow] = v1.y;
            As[lc4 + 18][lrow] = v1.z; As[lc4 + 19][lrow] = v1.w;
            const float* w = W + (size_t)(n0 + lrow) * K + k0 + lc4;
            const float4 u0 = *(const float4*)&w[0];
            const float4 u1 = *(const float4*)&w[16];
            Ws[lc4 + 0][lrow] = u0.x; Ws[lc4 + 1][lrow] = u0.y;
            Ws[lc4 + 2][lrow] = u0.z; Ws[lc4 + 3][lrow] = u0.w;
            Ws[lc4 + 16][lrow] = u1.x; Ws[lc4 + 17][lrow] = u1.y;
            Ws[lc4 + 18][lrow] = u1.z; Ws[lc4 + 19][lrow] = u1.w;
        }
        __syncthreads();
#pragma unroll
        for (int kk = 0; kk < 32; ++kk) {
            const float4 av = *(const float4*)&As[kk][ty * 4];
            const float4 wv = *(const float4*)&Ws[kk][tx * 4];
            const float a_[4] = {av.x, av.y, av.z, av.w};
            const float w_[4] = {wv.x, wv.y, wv.z, wv.w};
#pragma unroll
            for (int ri = 0; ri < 4; ++ri)
#pragma unroll
                for (int ci = 0; ci < 4; ++ci)
                    acc[ri][ci] = fmaf(a_[ri], w_[ci], acc[ri][ci]);
        }
        __syncthreads();
    }
#pragma unroll
    for (int ri = 0; ri < 4; ++ri)
#pragma unroll
        for (int ci = 0; ci < 4; ++ci) {
            const int row = m0 + ty * 4 + ri, col = n0 + tx * 4 + ci;
            C[(size_t)row * N + col] = acc[ri][ci] + bias[col];
        }
}

// ---------------------------------------------------------------------------
// bf16 MFMA GEMM (HW-validated round 5). GATE=1 fuses sigmoid-blend epilogue.
// ---------------------------------------------------------------------------
template <int GATE>
__global__ __launch_bounds__(256) void mfma_gemm_k(const float* __restrict__ A,
                                                   const float* __restrict__ A2,
                                                   const float* __restrict__ W,
                                                   const float* __restrict__ bias,
                                                   float* __restrict__ C,
                                                   int M, int K) {
    __shared__ ushort As[64][72];
    __shared__ ushort Ws[64][72];
    const int tid = threadIdx.x;
    const int m0 = blockIdx.x * 64, n0 = blockIdx.y * 64;
    const int w = tid >> 6, lane = tid & 63;
    const int wr = w >> 1, wc = w & 1;
    const int lr = lane & 15, lk = (lane >> 4) * 8;
    const int srow = tid >> 2, sc16 = (tid & 3) * 16;
    const int lda = GATE ? 256 : K;

    f32x4 acc[2][2];
#pragma unroll
    for (int i = 0; i < 2; ++i)
#pragma unroll
        for (int j = 0; j < 2; ++j) acc[i][j] = (f32x4){0.f, 0.f, 0.f, 0.f};

    const int nk = K / 64;
    for (int kt = 0; kt < nk; ++kt) {
        const float* srcA;
        int ka;
        if (GATE) {
            if (kt < 4) { srcA = A;  ka = kt * 64; }
            else        { srcA = A2; ka = (kt - 4) * 64; }
        } else { srcA = A; ka = kt * 64; }

        {
            const float* pa = srcA + (size_t)(m0 + srow) * lda + ka + sc16;
            const float* pw = W + (size_t)(n0 + srow) * K + kt * 64 + sc16;
#pragma unroll
            for (int q = 0; q < 4; ++q) {
                const float4 va = *(const float4*)&pa[q * 4];
                uint2 ua; ua.x = pack2bf(va.x, va.y); ua.y = pack2bf(va.z, va.w);
                *(uint2*)&As[srow][sc16 + q * 4] = ua;
                const float4 vw = *(const float4*)&pw[q * 4];
                uint2 uw; uw.x = pack2bf(vw.x, vw.y); uw.y = pack2bf(vw.z, vw.w);
                *(uint2*)&Ws[srow][sc16 + q * 4] = uw;
            }
        }
        __syncthreads();
#pragma unroll
        for (int kk = 0; kk < 2; ++kk) {
            bf16x8 af[2], bfr[2];
#pragma unroll
            for (int fm = 0; fm < 2; ++fm)
                af[fm] = *(const bf16x8*)&As[wr * 32 + fm * 16 + lr][kk * 32 + lk];
#pragma unroll
            for (int fn = 0; fn < 2; ++fn)
                bfr[fn] = *(const bf16x8*)&Ws[wc * 32 + fn * 16 + lr][kk * 32 + lk];
#pragma unroll
            for (int fm = 0; fm < 2; ++fm)
#pragma unroll
                for (int fn = 0; fn < 2; ++fn)
                    acc[fm][fn] = __builtin_amdgcn_mfma_f32_16x16x32_bf16(
                        af[fm], bfr[fn], acc[fm][fn], 0, 0, 0);
        }
        __syncthreads();
    }

#pragma unroll
    for (int fm = 0; fm < 2; ++fm)
#pragma unroll
        for (int fn = 0; fn < 2; ++fn) {
#pragma unroll
            for (int j = 0; j < 4; ++j) {
                const int row = m0 + wr * 32 + fm * 16 + (lane >> 4) * 4 + j;
                const int col = n0 + wc * 32 + fn * 16 + lr;
                const float v = acc[fm][fn][j] + bias[col];
                if (GATE) {
                    const float g = 1.f / (1.f + __expf(-v));
                    const float o  = A[(size_t)row * 256 + col];
                    const float oe = A2[(size_t)row * 256 + col];
                    C[(size_t)row * 256 + col] = g * o + (1.f - g) * oe;
                } else {
                    C[(size_t)row * 256 + col] = v;
                }
            }
        }
}

// ---------------------------------------------------------------------------
// Stage C: per-z env attention (f32, reference z-quirks kept).
// ---------------------------------------------------------------------------
__global__ __launch_bounds__(256) void env_attn_k(const float* __restrict__ Qp,
                                                  const float* __restrict__ Kp,
                                                  const float* __restrict__ Vp,
                                                  const float* __restrict__ envk,
                                                  const float* __restrict__ lam_p,
                                                  float* __restrict__ oute_pre) {
    const int gtid = blockIdx.x * 256 + threadIdx.x;
    const int z = gtid & 8191, b = gtid >> 13;
    const int i = z >> 3, j = z & 7, j2 = z >> 10;
    const float lam = lam_p[0];
    const float rs32 = 0.17677669529663687f;

    float4 q[8];
    const float* qrow = Qp + ((size_t)b * NN + i) * ND + j * HD;
#pragma unroll
    for (int t = 0; t < 8; ++t) q[t] = *(const float4*)&qrow[t * 4];

    float s[72];
    float mx = -3.0e38f;
#pragma unroll
    for (int c = 0; c < 8; ++c) {
        const float* kr = Kp + ((size_t)c * NN + i) * ND + j * HD;
        float d = 0.f;
#pragma unroll
        for (int t = 0; t < 8; ++t) d += dot4(q[t], *(const float4*)&kr[t * 4]);
        s[c] = d * rs32;
        mx = fmaxf(mx, s[c]);
    }
#pragma unroll
    for (int e = 0; e < 64; ++e) {
        const float* er = envk + (size_t)e * ND + j * HD;
        float d = 0.f;
#pragma unroll
        for (int t = 0; t < 8; ++t) d += dot4(q[t], *(const float4*)&er[t * 4]);
        s[8 + e] = lam * d * rs32;
        mx = fmaxf(mx, s[8 + e]);
    }
    float sum = 0.f;
#pragma unroll
    for (int k = 0; k < 72; ++k) { s[k] = __expf(s[k] - mx); sum += s[k]; }
    const float inv = 1.f / sum;

    float4 o[8];
#pragma unroll
    for (int t = 0; t < 8; ++t) o[t] = make_float4(0.f, 0.f, 0.f, 0.f);
#pragma unroll
    for (int c = 0; c < 8; ++c) {
        const float* vr = Vp + ((size_t)c * NN + i) * ND + j * HD;
        const float w = s[c] * inv;
#pragma unroll
        for (int t = 0; t < 8; ++t) {
            const float4 v = *(const float4*)&vr[t * 4];
            o[t].x += w * v.x; o[t].y += w * v.y; o[t].z += w * v.z; o[t].w += w * v.w;
        }
    }
#pragma unroll
    for (int e = 0; e < 64; ++e) {
        const float* er = envk + (size_t)e * ND + j2 * HD;
        const float w = s[8 + e] * inv;
#pragma unroll
        for (int t = 0; t < 8; ++t) {
            const float4 v = *(const float4*)&er[t * 4];
            o[t].x += w * v.x; o[t].y += w * v.y; o[t].z += w * v.z; o[t].w += w * v.w;
        }
    }
    float* orow = oute_pre + ((size_t)b * NN + i) * ND + j * HD;
#pragma unroll
    for (int t = 0; t < 8; ++t) *(float4*)&orow[t * 4] = o[t];
}

extern "C" void kernel_launch(void* const* d_in, const int* in_sizes, int n_in,
                              void* d_out, int out_size, void* d_ws, size_t ws_size,
                              hipStream_t stream) {
    const float* x          = (const float*)d_in[0];
    const float* conv_w     = (const float*)d_in[1];
    const float* conv_b     = (const float*)d_in[2];
    const float* phy_w      = (const float*)d_in[3];
    const float* phy_b      = (const float*)d_in[4];
    const float* to_out_w   = (const float*)d_in[5];
    const float* to_out_b   = (const float*)d_in[6];
    const float* env_keys   = (const float*)d_in[7];
    const float* env_proj_w = (const float*)d_in[8];
    const float* env_proj_b = (const float*)d_in[9];
    const float* lambda_    = (const float*)d_in[10];
    const float* q_w        = (const float*)d_in[11];
    const float* q_b        = (const float*)d_in[12];
    const float* k_w        = (const float*)d_in[13];
    const float* k_b        = (const float*)d_in[14];
    const float* v_w        = (const float*)d_in[15];
    const float* v_b        = (const float*)d_in[16];
    const float* out_proj_w = (const float*)d_in[17];
    const float* out_proj_b = (const float*)d_in[18];
    const float* gate_w     = (const float*)d_in[19];
    const float* gate_b     = (const float*)d_in[20];
    (void)in_sizes; (void)n_in; (void)out_size; (void)ws_size;

    float* ws     = (float*)d_ws;
    float* Sb     = ws;                  // 18432
    float* coefw  = Sb + 18432;          // 64
    float* pooledw= coefw + 64;          // 256
    float* envk   = pooledw + 256;       // 16384
    float* bufA   = envk + 16384;        // 2M : attn_out -> oute_pre
    float* bufB   = bufA + 2097152;      // 2M : out (physics branch)
    float* bufC   = bufB + 2097152;      // 2M : Qp -> oute
    float* bufD   = bufC + 2097152;      // 2M : Kp
    float* Vp     = (float*)d_out;       // Vp liveness ends before gate writes

    hipMemsetAsync(Sb, 0, 18432 * sizeof(float), stream);
    conv_sums_k<<<dim3(16, 8), 256, 0, stream>>>(x, Sb);
    pooled_k<<<256, 64, 0, stream>>>(Sb, conv_w, conv_b, pooledw);
    phy_coef_k<<<1, 64, 0, stream>>>(pooledw, phy_w, phy_b, coefw);

    phys_attn_mfma_k<<<dim3(8, 64), 256, 0, stream>>>(x, coefw, bufA);
    mfma_gemm_k<0><<<dim3(128, 4), 256, 0, stream>>>(bufA, nullptr, to_out_w,
                                                     to_out_b, bufB, 8192, 256);

    mfma_gemm_k<0><<<dim3(128, 4), 256, 0, stream>>>(x, nullptr, q_w, q_b, bufC,
                                                     8192, 256);
    mfma_gemm_k<0><<<dim3(128, 4), 256, 0, stream>>>(x, nullptr, k_w, k_b, bufD,
                                                     8192, 256);
    mfma_gemm_k<0><<<dim3(128, 4), 256, 0, stream>>>(x, nullptr, v_w, v_b, Vp,
                                                     8192, 256);
    gemm_tn_k<<<dim3(1, 4), 256, 0, stream>>>(env_keys, env_proj_w, env_proj_b,
                                              envk, 64, 256, 256);

    env_attn_k<<<256, 256, 0, stream>>>(bufC, bufD, Vp, envk, lambda_, bufA);
    mfma_gemm_k<0><<<dim3(128, 4), 256, 0, stream>>>(bufA, nullptr, out_proj_w,
                                                     out_proj_b, bufC, 8192, 256);

    mfma_gemm_k<1><<<dim3(128, 4), 256, 0, stream>>>(bufB, bufC, gate_w, gate_b,
                                                     (float*)d_out, 8192, 512);
}

// Round 13
// 298.048 us; speedup vs baseline: 1.8412x; 1.1643x over previous
//
#include <hip/hip_runtime.h>
#include <hip/hip_bf16.h>
#include <cstdint>
#include <cstddef>

#define NB 8
#define NN 1024
#define ND 256
#define NH 8
#define HD 32

typedef __attribute__((ext_vector_type(8))) short bf16x8;
typedef __attribute__((ext_vector_type(4))) float f32x4;

static __device__ __forceinline__ float dot4(float4 a, float4 b) {
    return a.x * b.x + a.y * b.y + a.z * b.z + a.w * b.w;
}

static __device__ __forceinline__ uint32_t pack2bf(float x, float y) {
    __hip_bfloat16 bx = __float2bfloat16(x), by = __float2bfloat16(y);
    return (uint32_t)(*reinterpret_cast<uint16_t*>(&bx)) |
           ((uint32_t)(*reinterpret_cast<uint16_t*>(&by)) << 16);
}

static __device__ __forceinline__ ushort bf1(float x) {
    __hip_bfloat16 b = __float2bfloat16(x);
    return *reinterpret_cast<uint16_t*>(&b);
}

// ---------------------------------------------------------------------------
// Stage A1: shifted sums for conv-mean algebra. Grid (16,8) for TLP.
// ---------------------------------------------------------------------------
__global__ __launch_bounds__(256) void conv_sums_k(const float* __restrict__ x,
                                                   float* __restrict__ S) {
    const int b = blockIdx.y;
    const int q = blockIdx.x;
    const int c = threadIdx.x;
    const float* xb = x + (size_t)b * (NN * ND) + c;
    float T = 0.f, R0 = 0.f, R31 = 0.f, C0 = 0.f, C31 = 0.f;
    float c00 = 0.f, c0N = 0.f, cN0 = 0.f, cNN = 0.f;
    const int n0 = q * 64;
    for (int nn = 0; nn < 64; ++nn) {
        const int n = n0 + nn;
        const float v = xb[(size_t)n * ND];
        T += v;
        if (n < 32)   R0 += v;
        if (n >= 992) R31 += v;
        const int j = n & 31;
        if (j == 0)  C0 += v;
        if (j == 31) C31 += v;
        if (n == 0)    c00 = v;
        if (n == 31)   c0N = v;
        if (n == 992)  cN0 = v;
        if (n == 1023) cNN = v;
    }
    float* Sp = S + (size_t)b * 2304 + c * 9;
    atomicAdd(&Sp[0], T - R31 - C31 + cNN);
    atomicAdd(&Sp[1], T - R31);
    atomicAdd(&Sp[2], T - R31 - C0 + cN0);
    atomicAdd(&Sp[3], T - C31);
    atomicAdd(&Sp[4], T);
    atomicAdd(&Sp[5], T - C0);
    atomicAdd(&Sp[6], T - R0 - C31 + c0N);
    atomicAdd(&Sp[7], T - R0);
    atomicAdd(&Sp[8], T - R0 - C0 + c00);
}

// ---------------------------------------------------------------------------
// Stage A2a: pooled[b,o] = conv_b[o] + dot(conv_w[o], S[b])/1024.
// ---------------------------------------------------------------------------
__global__ __launch_bounds__(64) void pooled_k(const float* __restrict__ S,
                                               const float* __restrict__ conv_w,
                                               const float* __restrict__ conv_b,
                                               float* __restrict__ pooled) {
    const int bx = blockIdx.x;
    const int b = bx >> 5, o = bx & 31;
    const int t = threadIdx.x;
    const float4* w4 = (const float4*)(conv_w + (size_t)o * 2304);
    const float4* s4 = (const float4*)(S + (size_t)b * 2304);
    float acc = 0.f;
#pragma unroll
    for (int f = 0; f < 9; ++f) acc += dot4(w4[f * 64 + t], s4[f * 64 + t]);
    acc += __shfl_xor(acc, 1);  acc += __shfl_xor(acc, 2);
    acc += __shfl_xor(acc, 4);  acc += __shfl_xor(acc, 8);
    acc += __shfl_xor(acc, 16); acc += __shfl_xor(acc, 32);
    if (t == 0) pooled[b * 32 + o] = conv_b[o] + acc * (1.f / 1024.f);
}

// ---------------------------------------------------------------------------
// Stage A2b: phy = pooled @ phy_w.T + phy_b ; coef = scale*scat/(atten+1e-6).
// ---------------------------------------------------------------------------
__global__ __launch_bounds__(64) void phy_coef_k(const float* __restrict__ pooled,
                                                 const float* __restrict__ phy_w,
                                                 const float* __restrict__ phy_b,
                                                 float* __restrict__ coef) {
    __shared__ float ps[8][32];
    const int t = threadIdx.x;
#pragma unroll
    for (int r = 0; r < 4; ++r) {
        const int idx = r * 64 + t;
        ps[idx >> 5][idx & 31] = pooled[idx];
    }
    __syncthreads();
    const int b = t & 7, hh = t >> 3;
    float atten = phy_b[hh], scat = phy_b[8 + hh];
#pragma unroll
    for (int l = 0; l < 32; ++l) {
        atten += ps[b][l] * phy_w[hh * 32 + l];
        scat  += ps[b][l] * phy_w[(8 + hh) * 32 + l];
    }
    coef[b * 8 + hh] = 0.17677669529663687f * scat / (atten + 1e-6f);
}

// ---------------------------------------------------------------------------
// Stage B: MFMA physics flash attention (validated round 6: 196 -> off top-5).
// ---------------------------------------------------------------------------
__global__ __launch_bounds__(256) void phys_attn_mfma_k(const float* __restrict__ x,
                                                        const float* __restrict__ coef,
                                                        float* __restrict__ attn_out) {
    const int bh = blockIdx.y;
    const int b = bh >> 3, h = bh & 7;
    const int wv = threadIdx.x >> 6, lane = threadIdx.x & 63;
    const int g = lane >> 4, c16 = lane & 15;
    const float cf = coef[bh];
    const float* xb = x + (size_t)b * (NN * ND) + h * HD;

    __shared__ ushort Kl[2][32][40];
    __shared__ ushort VT[2][32][40];

    bf16x8 qf[2];
    const int q0 = blockIdx.x * 128 + wv * 32;
#pragma unroll
    for (int fq = 0; fq < 2; ++fq) {
        const float* qr = xb + (size_t)(q0 + fq * 16 + c16) * ND + g * 8;
        const float4 v0 = *(const float4*)&qr[0];
        const float4 v1 = *(const float4*)&qr[4];
        union { bf16x8 v; uint32_t u[4]; } qq;
        qq.u[0] = pack2bf(v0.x * cf, v0.y * cf);
        qq.u[1] = pack2bf(v0.z * cf, v0.w * cf);
        qq.u[2] = pack2bf(v1.x * cf, v1.y * cf);
        qq.u[3] = pack2bf(v1.z * cf, v1.w * cf);
        qf[fq] = qq.v;
    }

    const int skv = threadIdx.x >> 3, sdq = (threadIdx.x & 7) * 4;
    {
        const float4 v = *(const float4*)&xb[(size_t)skv * ND + sdq];
        const ushort e0 = bf1(v.x), e1 = bf1(v.y), e2 = bf1(v.z), e3 = bf1(v.w);
        uint2 kw; kw.x = (uint32_t)e0 | ((uint32_t)e1 << 16);
        kw.y = (uint32_t)e2 | ((uint32_t)e3 << 16);
        *(uint2*)&Kl[0][skv][sdq] = kw;
        VT[0][sdq + 0][skv] = e0; VT[0][sdq + 1][skv] = e1;
        VT[0][sdq + 2][skv] = e2; VT[0][sdq + 3][skv] = e3;
    }
    __syncthreads();

    f32x4 oacc[2][2];
#pragma unroll
    for (int i = 0; i < 2; ++i)
#pragma unroll
        for (int j = 0; j < 2; ++j) oacc[i][j] = (f32x4){0.f, 0.f, 0.f, 0.f};
    float m[2] = {-3.0e38f, -3.0e38f};
    float lsum[2] = {0.f, 0.f};

    const int srcA = c16 + (((2 * g) & 3) << 4);
    const int srcB = c16 + (((2 * g + 1) & 3) << 4);
    const int srcQ = (lane & 48) | (g * 4);

    for (int c = 0; c < 16 * 2; ++c) {
        const int cur = c & 1;
        float4 nv;
        const bool hasNext = (c + 1 < 32);
        if (hasNext)
            nv = *(const float4*)&xb[(size_t)((c + 1) * 32 + skv) * ND + sdq];

        const bf16x8 af0 = *(const bf16x8*)&Kl[cur][c16][g * 8];
        const bf16x8 af1 = *(const bf16x8*)&Kl[cur][16 + c16][g * 8];
        f32x4 sacc[2][2];
        const f32x4 z4 = (f32x4){0.f, 0.f, 0.f, 0.f};
        sacc[0][0] = __builtin_amdgcn_mfma_f32_16x16x32_bf16(af0, qf[0], z4, 0, 0, 0);
        sacc[0][1] = __builtin_amdgcn_mfma_f32_16x16x32_bf16(af0, qf[1], z4, 0, 0, 0);
        sacc[1][0] = __builtin_amdgcn_mfma_f32_16x16x32_bf16(af1, qf[0], z4, 0, 0, 0);
        sacc[1][1] = __builtin_amdgcn_mfma_f32_16x16x32_bf16(af1, qf[1], z4, 0, 0, 0);

        bf16x8 pa[2];
        float corrS[2];
#pragma unroll
        for (int fq = 0; fq < 2; ++fq) {
            float vmax = sacc[0][fq][0];
#pragma unroll
            for (int j = 1; j < 4; ++j) vmax = fmaxf(vmax, sacc[0][fq][j]);
#pragma unroll
            for (int j = 0; j < 4; ++j) vmax = fmaxf(vmax, sacc[1][fq][j]);
            vmax = fmaxf(vmax, __shfl_xor(vmax, 16));
            vmax = fmaxf(vmax, __shfl_xor(vmax, 32));
            const float mn = fmaxf(m[fq], vmax);
            corrS[fq] = __expf(m[fq] - mn);
            m[fq] = mn;
            float p[2][4];
            float rs = 0.f;
#pragma unroll
            for (int fkv = 0; fkv < 2; ++fkv)
#pragma unroll
                for (int j = 0; j < 4; ++j) {
                    p[fkv][j] = __expf(sacc[fkv][fq][j] - mn);
                    rs += p[fkv][j];
                }
            rs += __shfl_xor(rs, 16);
            rs += __shfl_xor(rs, 32);
            lsum[fq] = lsum[fq] * corrS[fq] + rs;

            uint32_t pk00 = pack2bf(p[0][0], p[0][1]);
            uint32_t pk01 = pack2bf(p[0][2], p[0][3]);
            uint32_t pk10 = pack2bf(p[1][0], p[1][1]);
            uint32_t pk11 = pack2bf(p[1][2], p[1][3]);
            const int t00 = __shfl((int)pk00, srcA), t10 = __shfl((int)pk10, srcA);
            const int t01 = __shfl((int)pk01, srcA), t11 = __shfl((int)pk11, srcA);
            const int t02 = __shfl((int)pk00, srcB), t12 = __shfl((int)pk10, srcB);
            const int t03 = __shfl((int)pk01, srcB), t13 = __shfl((int)pk11, srcB);
            union { bf16x8 v; uint32_t u[4]; } pu;
            const bool hi = (g >> 1) != 0;
            pu.u[0] = (uint32_t)(hi ? t10 : t00);
            pu.u[1] = (uint32_t)(hi ? t11 : t01);
            pu.u[2] = (uint32_t)(hi ? t12 : t02);
            pu.u[3] = (uint32_t)(hi ? t13 : t03);
            pa[fq] = pu.v;
        }

#pragma unroll
        for (int fq = 0; fq < 2; ++fq) {
#pragma unroll
            for (int j = 0; j < 4; ++j) {
                const float cj = __shfl(corrS[fq], srcQ + j);
                oacc[fq][0][j] *= cj;
                oacc[fq][1][j] *= cj;
            }
        }

        const bf16x8 bv0 = *(const bf16x8*)&VT[cur][c16][g * 8];
        const bf16x8 bv1 = *(const bf16x8*)&VT[cur][16 + c16][g * 8];
        oacc[0][0] = __builtin_amdgcn_mfma_f32_16x16x32_bf16(pa[0], bv0, oacc[0][0], 0, 0, 0);
        oacc[0][1] = __builtin_amdgcn_mfma_f32_16x16x32_bf16(pa[0], bv1, oacc[0][1], 0, 0, 0);
        oacc[1][0] = __builtin_amdgcn_mfma_f32_16x16x32_bf16(pa[1], bv0, oacc[1][0], 0, 0, 0);
        oacc[1][1] = __builtin_amdgcn_mfma_f32_16x16x32_bf16(pa[1], bv1, oacc[1][1], 0, 0, 0);

        if (hasNext) {
            const ushort e0 = bf1(nv.x), e1 = bf1(nv.y), e2 = bf1(nv.z), e3 = bf1(nv.w);
            uint2 kw; kw.x = (uint32_t)e0 | ((uint32_t)e1 << 16);
            kw.y = (uint32_t)e2 | ((uint32_t)e3 << 16);
            *(uint2*)&Kl[cur ^ 1][skv][sdq] = kw;
            VT[cur ^ 1][sdq + 0][skv] = e0; VT[cur ^ 1][sdq + 1][skv] = e1;
            VT[cur ^ 1][sdq + 2][skv] = e2; VT[cur ^ 1][sdq + 3][skv] = e3;
        }
        __syncthreads();
    }

#pragma unroll
    for (int fq = 0; fq < 2; ++fq) {
        const float inv = 1.f / lsum[fq];
#pragma unroll
        for (int j = 0; j < 4; ++j) {
            const float iv = __shfl(inv, srcQ + j);
            const int row = q0 + fq * 16 + g * 4 + j;
            float* orow = attn_out + (size_t)(b * NN + row) * ND + h * HD;
            orow[c16]      = oacc[fq][0][j] * iv;
            orow[16 + c16] = oacc[fq][1][j] * iv;
        }
    }
}

// ---------------------------------------------------------------------------
// Generic f32 GEMM (tiny envk GEMM only).
// ---------------------------------------------------------------------------
__global__ __launch_bounds__(256) void gemm_tn_k(const float* __restrict__ A,
                                                 const float* __restrict__ W,
                                                 const float* __restrict__ bias,
                                                 float* __restrict__ C,
                                                 int M, int N, int K) {
    __shared__ __align__(16) float As[32][64];
    __shared__ __align__(16) float Ws[32][64];
    const int tid = threadIdx.x;
    const int m0 = blockIdx.x * 64, n0 = blockIdx.y * 64;
    const int tx = tid & 15, ty = tid >> 4;
    const int lrow = tid >> 2, lc4 = (tid & 3) * 4;
    float acc[4][4] = {{0.f}};
    for (int k0 = 0; k0 < K; k0 += 32) {
        {
            const float* a = A + (size_t)(m0 + lrow) * K + k0 + lc4;
            const float4 v0 = *(const float4*)&a[0];
            const float4 v1 = *(const float4*)&a[16];
            As[lc4 + 0][lrow] = v0.x; As[lc4 + 1][lrow] = v0.y;
            As[lc4 + 2][lrow] = v0.z; As[lc4 + 3][lrow] = v0.w;
            As[lc4 + 16][lrow] = v1.x; As[lc4 + 17][lrow] = v1.y;
            As[lc4 + 18][lrow] = v1.z; As[lc4 + 19][lrow] = v1.w;
            const float* w = W + (size_t)(n0 + lrow) * K + k0 + lc4;
            const float4 u0 = *(const float4*)&w[0];
            const float4 u1 = *(const float4*)&w[16];
            Ws[lc4 + 0][lrow] = u0.x; Ws[lc4 + 1][lrow] = u0.y;
            Ws[lc4 + 2][lrow] = u0.z; Ws[lc4 + 3][lrow] = u0.w;
            Ws[lc4 + 16][lrow] = u1.x; Ws[lc4 + 17][lrow] = u1.y;
            Ws[lc4 + 18][lrow] = u1.z; Ws[lc4 + 19][lrow] = u1.w;
        }
        __syncthreads();
#pragma unroll
        for (int kk = 0; kk < 32; ++kk) {
            const float4 av = *(const float4*)&As[kk][ty * 4];
            const float4 wv = *(const float4*)&Ws[kk][tx * 4];
            const float a_[4] = {av.x, av.y, av.z, av.w};
            const float w_[4] = {wv.x, wv.y, wv.z, wv.w};
#pragma unroll
            for (int ri = 0; ri < 4; ++ri)
#pragma unroll
                for (int ci = 0; ci < 4; ++ci)
                    acc[ri][ci] = fmaf(a_[ri], w_[ci], acc[ri][ci]);
        }
        __syncthreads();
    }
#pragma unroll
    for (int ri = 0; ri < 4; ++ri)
#pragma unroll
        for (int ci = 0; ci < 4; ++ci) {
            const int row = m0 + ty * 4 + ri, col = n0 + tx * 4 + ci;
            C[(size_t)row * N + col] = acc[ri][ci] + bias[col];
        }
}

// ---------------------------------------------------------------------------
// bf16 MFMA GEMM (HW-validated round 5). GATE=1 fuses sigmoid-blend epilogue.
// ---------------------------------------------------------------------------
template <int GATE>
__global__ __launch_bounds__(256) void mfma_gemm_k(const float* __restrict__ A,
                                                   const float* __restrict__ A2,
                                                   const float* __restrict__ W,
                                                   const float* __restrict__ bias,
                                                   float* __restrict__ C,
                                                   int M, int K) {
    __shared__ ushort As[64][72];
    __shared__ ushort Ws[64][72];
    const int tid = threadIdx.x;
    const int m0 = blockIdx.x * 64, n0 = blockIdx.y * 64;
    const int w = tid >> 6, lane = tid & 63;
    const int wr = w >> 1, wc = w & 1;
    const int lr = lane & 15, lk = (lane >> 4) * 8;
    const int srow = tid >> 2, sc16 = (tid & 3) * 16;
    const int lda = GATE ? 256 : K;

    f32x4 acc[2][2];
#pragma unroll
    for (int i = 0; i < 2; ++i)
#pragma unroll
        for (int j = 0; j < 2; ++j) acc[i][j] = (f32x4){0.f, 0.f, 0.f, 0.f};

    const int nk = K / 64;
    for (int kt = 0; kt < nk; ++kt) {
        const float* srcA;
        int ka;
        if (GATE) {
            if (kt < 4) { srcA = A;  ka = kt * 64; }
            else        { srcA = A2; ka = (kt - 4) * 64; }
        } else { srcA = A; ka = kt * 64; }

        {
            const float* pa = srcA + (size_t)(m0 + srow) * lda + ka + sc16;
            const float* pw = W + (size_t)(n0 + srow) * K + kt * 64 + sc16;
#pragma unroll
            for (int q = 0; q < 4; ++q) {
                const float4 va = *(const float4*)&pa[q * 4];
                uint2 ua; ua.x = pack2bf(va.x, va.y); ua.y = pack2bf(va.z, va.w);
                *(uint2*)&As[srow][sc16 + q * 4] = ua;
                const float4 vw = *(const float4*)&pw[q * 4];
                uint2 uw; uw.x = pack2bf(vw.x, vw.y); uw.y = pack2bf(vw.z, vw.w);
                *(uint2*)&Ws[srow][sc16 + q * 4] = uw;
            }
        }
        __syncthreads();
#pragma unroll
        for (int kk = 0; kk < 2; ++kk) {
            bf16x8 af[2], bfr[2];
#pragma unroll
            for (int fm = 0; fm < 2; ++fm)
                af[fm] = *(const bf16x8*)&As[wr * 32 + fm * 16 + lr][kk * 32 + lk];
#pragma unroll
            for (int fn = 0; fn < 2; ++fn)
                bfr[fn] = *(const bf16x8*)&Ws[wc * 32 + fn * 16 + lr][kk * 32 + lk];
#pragma unroll
            for (int fm = 0; fm < 2; ++fm)
#pragma unroll
                for (int fn = 0; fn < 2; ++fn)
                    acc[fm][fn] = __builtin_amdgcn_mfma_f32_16x16x32_bf16(
                        af[fm], bfr[fn], acc[fm][fn], 0, 0, 0);
        }
        __syncthreads();
    }

#pragma unroll
    for (int fm = 0; fm < 2; ++fm)
#pragma unroll
        for (int fn = 0; fn < 2; ++fn) {
#pragma unroll
            for (int j = 0; j < 4; ++j) {
                const int row = m0 + wr * 32 + fm * 16 + (lane >> 4) * 4 + j;
                const int col = n0 + wc * 32 + fn * 16 + lr;
                const float v = acc[fm][fn][j] + bias[col];
                if (GATE) {
                    const float g = 1.f / (1.f + __expf(-v));
                    const float o  = A[(size_t)row * 256 + col];
                    const float oe = A2[(size_t)row * 256 + col];
                    C[(size_t)row * 256 + col] = g * o + (1.f - g) * oe;
                } else {
                    C[(size_t)row * 256 + col] = v;
                }
            }
        }
}

// ---------------------------------------------------------------------------
// Stage C v2: env attention, split-d by 4. Quad of lanes (dq=0..3) shares one
// (b,z); each lane owns 8 d-elements. Scores = partial dots + 2 quad-shfls.
// Wave's 32 lanes cover a full 1KB row contiguously (coalesced); env rows are
// wave-broadcast. Softmax redundant per quad. Reference z-quirks kept
// (scores use j=z&7; env-V uses j2=z>>10).
// ---------------------------------------------------------------------------
__global__ __launch_bounds__(256) void env_attn_k(const float* __restrict__ Qp,
                                                  const float* __restrict__ Kp,
                                                  const float* __restrict__ Vp,
                                                  const float* __restrict__ envk,
                                                  const float* __restrict__ lam_p,
                                                  float* __restrict__ oute_pre) {
    const int gtid = blockIdx.x * 256 + threadIdx.x;
    const int dq = gtid & 3;
    const int z = (gtid >> 2) & 8191;
    const int b = gtid >> 15;
    const int i = z >> 3, j = z & 7, j2 = z >> 10;
    const float lam = lam_p[0];
    const float rs32 = 0.17677669529663687f;
    const int dof = j * HD + dq * 8;

    const float* qrow = Qp + ((size_t)b * NN + i) * ND + dof;
    const float4 q0 = *(const float4*)&qrow[0];
    const float4 q1 = *(const float4*)&qrow[4];

    float s[72];
#pragma unroll
    for (int c = 0; c < 8; ++c) {
        const float* kr = Kp + ((size_t)c * NN + i) * ND + dof;
        s[c] = dot4(q0, *(const float4*)&kr[0]) + dot4(q1, *(const float4*)&kr[4]);
    }
#pragma unroll
    for (int e = 0; e < 64; ++e) {
        const float* er = envk + (size_t)e * ND + dof;
        s[8 + e] = dot4(q0, *(const float4*)&er[0]) + dot4(q1, *(const float4*)&er[4]);
    }
    // quad butterfly: full 32-d dot in all 4 lanes
#pragma unroll
    for (int k = 0; k < 72; ++k) {
        s[k] += __shfl_xor(s[k], 1);
        s[k] += __shfl_xor(s[k], 2);
    }
    float mx = -3.0e38f;
#pragma unroll
    for (int c = 0; c < 8; ++c) { s[c] *= rs32; mx = fmaxf(mx, s[c]); }
    const float lr32 = lam * rs32;
#pragma unroll
    for (int e = 0; e < 64; ++e) { s[8 + e] *= lr32; mx = fmaxf(mx, s[8 + e]); }
    float sum = 0.f;
#pragma unroll
    for (int k = 0; k < 72; ++k) { s[k] = __expf(s[k] - mx); sum += s[k]; }
    const float inv = 1.f / sum;

    float4 o0 = make_float4(0.f, 0.f, 0.f, 0.f);
    float4 o1 = make_float4(0.f, 0.f, 0.f, 0.f);
#pragma unroll
    for (int c = 0; c < 8; ++c) {
        const float* vr = Vp + ((size_t)c * NN + i) * ND + dof;
        const float w = s[c] * inv;
        const float4 v0 = *(const float4*)&vr[0];
        const float4 v1 = *(const float4*)&vr[4];
        o0.x += w * v0.x; o0.y += w * v0.y; o0.z += w * v0.z; o0.w += w * v0.w;
        o1.x += w * v1.x; o1.y += w * v1.y; o1.z += w * v1.z; o1.w += w * v1.w;
    }
    const int dof2 = j2 * HD + dq * 8;
#pragma unroll
    for (int e = 0; e < 64; ++e) {
        const float* er = envk + (size_t)e * ND + dof2;
        const float w = s[8 + e] * inv;
        const float4 v0 = *(const float4*)&er[0];
        const float4 v1 = *(const float4*)&er[4];
        o0.x += w * v0.x; o0.y += w * v0.y; o0.z += w * v0.z; o0.w += w * v0.w;
        o1.x += w * v1.x; o1.y += w * v1.y; o1.z += w * v1.z; o1.w += w * v1.w;
    }
    float* orow = oute_pre + ((size_t)b * NN + i) * ND + dof;
    *(float4*)&orow[0] = o0;
    *(float4*)&orow[4] = o1;
}

extern "C" void kernel_launch(void* const* d_in, const int* in_sizes, int n_in,
                              void* d_out, int out_size, void* d_ws, size_t ws_size,
                              hipStream_t stream) {
    const float* x          = (const float*)d_in[0];
    const float* conv_w     = (const float*)d_in[1];
    const float* conv_b     = (const float*)d_in[2];
    const float* phy_w      = (const float*)d_in[3];
    const float* phy_b      = (const float*)d_in[4];
    const float* to_out_w   = (const float*)d_in[5];
    const float* to_out_b   = (const float*)d_in[6];
    const float* env_keys   = (const float*)d_in[7];
    const float* env_proj_w = (const float*)d_in[8];
    const float* env_proj_b = (const float*)d_in[9];
    const float* lambda_    = (const float*)d_in[10];
    const float* q_w        = (const float*)d_in[11];
    const float* q_b        = (const float*)d_in[12];
    const float* k_w        = (const float*)d_in[13];
    const float* k_b        = (const float*)d_in[14];
    const float* v_w        = (const float*)d_in[15];
    const float* v_b        = (const float*)d_in[16];
    const float* out_proj_w = (const float*)d_in[17];
    const float* out_proj_b = (const float*)d_in[18];
    const float* gate_w     = (const float*)d_in[19];
    const float* gate_b     = (const float*)d_in[20];
    (void)in_sizes; (void)n_in; (void)out_size; (void)ws_size;

    float* ws     = (float*)d_ws;
    float* Sb     = ws;                  // 18432
    float* coefw  = Sb + 18432;          // 64
    float* pooledw= coefw + 64;          // 256
    float* envk   = pooledw + 256;       // 16384
    float* bufA   = envk + 16384;        // 2M : attn_out -> oute_pre
    float* bufB   = bufA + 2097152;      // 2M : out (physics branch)
    float* bufC   = bufB + 2097152;      // 2M : Qp -> oute
    float* bufD   = bufC + 2097152;      // 2M : Kp
    float* Vp     = (float*)d_out;       // Vp liveness ends before gate writes

    hipMemsetAsync(Sb, 0, 18432 * sizeof(float), stream);
    conv_sums_k<<<dim3(16, 8), 256, 0, stream>>>(x, Sb);
    pooled_k<<<256, 64, 0, stream>>>(Sb, conv_w, conv_b, pooledw);
    phy_coef_k<<<1, 64, 0, stream>>>(pooledw, phy_w, phy_b, coefw);

    phys_attn_mfma_k<<<dim3(8, 64), 256, 0, stream>>>(x, coefw, bufA);
    mfma_gemm_k<0><<<dim3(128, 4), 256, 0, stream>>>(bufA, nullptr, to_out_w,
                                                     to_out_b, bufB, 8192, 256);

    mfma_gemm_k<0><<<dim3(128, 4), 256, 0, stream>>>(x, nullptr, q_w, q_b, bufC,
                                                     8192, 256);
    mfma_gemm_k<0><<<dim3(128, 4), 256, 0, stream>>>(x, nullptr, k_w, k_b, bufD,
                                                     8192, 256);
    mfma_gemm_k<0><<<dim3(128, 4), 256, 0, stream>>>(x, nullptr, v_w, v_b, Vp,
                                                     8192, 256);
    gemm_tn_k<<<dim3(1, 4), 256, 0, stream>>>(env_keys, env_proj_w, env_proj_b,
                                              envk, 64, 256, 256);

    env_attn_k<<<1024, 256, 0, stream>>>(bufC, bufD, Vp, envk, lambda_, bufA);
    mfma_gemm_k<0><<<dim3(128, 4), 256, 0, stream>>>(bufA, nullptr, out_proj_w,
                                                     out_proj_b, bufC, 8192, 256);

    mfma_gemm_k<1><<<dim3(128, 4), 256, 0, stream>>>(bufB, bufC, gate_w, gate_b,
                                                     (float*)d_out, 8192, 512);
}